// Round 10
// baseline (75.607 us; speedup 1.0000x reference)
//
#include <hip/hip_runtime.h>

// ConcatenationAttention: B=8, S=1024, H=128, A=16
// out[b,i,:] = sum_{j<i} w_ij * x[b,j,:],  w = softmax over j of
//   score(i,j) = sum_a w2[a]*tanh(f[b,i,a] + g[b,j,a] + b1[a]) + b2
//
// Round 10: round-9 fixed (nontemporal builtins need ext_vector, not float4).
// 8704 waves (8 i x 64 j chunks, 8 waves/SIMD) + XCD-batch pinning (b=bid&7)
// + non-temporal pacc stores + factorized exp2 (1 trans/term).

#define B_ 8
#define S_ 1024
#define H_ 128
#define A_ 16
#define TI 16
#define JC 64
#define PC_PER_B 1088          // per-batch chunks: sum_{k=0}^{15} 8*(k+1)
#define NCH (B_ * PC_PER_B)    // 8704 chunk-waves

typedef float f32x2 __attribute__((ext_vector_type(2)));
typedef float f32x4 __attribute__((ext_vector_type(4)));

// acc += e2 * broadcast(x2.lo)
__device__ __forceinline__ void pk_fma_bl(f32x2& acc, f32x2 e2, f32x2 x2) {
  asm volatile("v_pk_fma_f32 %0, %1, %2, %0 op_sel:[0,0,0] op_sel_hi:[1,0,1]"
               : "+v"(acc) : "v"(e2), "v"(x2));
}
// acc += e2 * broadcast(x2.hi)
__device__ __forceinline__ void pk_fma_bh(f32x2& acc, f32x2 e2, f32x2 x2) {
  asm volatile("v_pk_fma_f32 %0, %1, %2, %0 op_sel:[0,1,0] op_sel_hi:[1,1,1]"
               : "+v"(acc) : "v"(e2), "v"(x2));
}

__global__ __launch_bounds__(256) void fg_kernel(
    const float* __restrict__ x, const float* __restrict__ W1,
    const float* __restrict__ b1, float* __restrict__ f2,
    float* __restrict__ g2) {
  int gid = blockIdx.x * 256 + threadIdx.x;   // B*S*32 threads
  int row = gid >> 5;                         // b*S + s
  int q = gid & 31;
  int a = q & 15;
  int half = q >> 4;
  const float4* x4 = reinterpret_cast<const float4*>(x + (size_t)row * H_);
  const float* w = W1 + half * H_ * A_ + a;   // column a, stride A_
  float s = 0.f;
#pragma unroll 4
  for (int hi = 0; hi < H_ / 4; ++hi) {
    float4 xv = x4[hi];
    s = fmaf(xv.x, w[(hi * 4 + 0) * A_], s);
    s = fmaf(xv.y, w[(hi * 4 + 1) * A_], s);
    s = fmaf(xv.z, w[(hi * 4 + 2) * A_], s);
    s = fmaf(xv.w, w[(hi * 4 + 3) * A_], s);
  }
  const float TANH_C = 2.8853900817779268f;   // 2*log2(e)
  // Store exp2-domain values: F = exp2((f+b1)*C), E = exp2(g*C).
  if (half == 0)
    f2[row * A_ + a] = __builtin_amdgcn_exp2f((s + b1[a]) * TANH_C);
  else
    g2[row * A_ + a] = __builtin_amdgcn_exp2f(s * TANH_C);
}

// -------- round 10: XCD-pinned i-split flat chunks, nt stores --------------
// block bid: batch b = bid&7 (XCD-local), per-batch chunk pc = (bid>>3)*4+wv.
// Group k in [0,16): half-tiles ht=8k+r (r<8), k+1 chunks each;
// pc = 4k(k+1) + r*(k+1) + c.  slot = bid*4+wv.
__global__ __launch_bounds__(256, 8) void attn_flat9(
    const float* __restrict__ x, const float* __restrict__ f2,
    const float* __restrict__ g2, const float* __restrict__ w2,
    const float* __restrict__ b2, float* __restrict__ pacc,
    float* __restrict__ pden) {
  __shared__ __align__(16) float es[4][JC * 8];  // [wave][j][il], 2 KB/wave

  const int tid = threadIdx.x;
  const int wv = tid >> 6;
  const int lane = tid & 63;
  const int bid = blockIdx.x;
  const int b = bid & 7;                       // XCD-pinned batch
  const int pc = ((bid >> 3) << 2) + wv;       // per-batch chunk [0,1088)
  int k = (int)((__builtin_sqrtf((float)pc + 1.0f) - 1.0f) * 0.5f);
  while (4 * (k + 1) * (k + 2) <= pc) ++k;
  while (4 * k * (k + 1) > pc) --k;
  const int rem = pc - 4 * k * (k + 1);
  const int r = rem / (k + 1);
  const int c = rem - r * (k + 1);
  const int ht = (k << 3) + r;
  const int i0 = ht << 3;
  const int jbase = c << 6;
  const int slot = (bid << 2) + wv;

  const float LOG2E = 1.4426950408889634f;
  float w2s[16];
  float K;
  {
    float sw = 0.f;
#pragma unroll
    for (int a = 0; a < 16; ++a) {
      float v = w2[a];
      w2s[a] = v * (2.f * LOG2E);
      sw += v;
    }
    K = (sw + b2[0]) * LOG2E;
  }

  const int th = lane >> 5;
  const int hq = lane & 31;
  float* esw = &es[wv][0];
  float4* esw4w = reinterpret_cast<float4*>(esw);
  const float4* esw4 = reinterpret_cast<const float4*>(esw);

  f32x2 acc2[8];  // [pr*4+h]: rows th*4+2pr(+1), cols hq*4+h
#pragma unroll
  for (int p = 0; p < 8; ++p) acc2[p] = (f32x2){0.f, 0.f};

  // ---- score: lane owns column j; E row in VGPRs, F rows scalar loads ----
  {
    const int j = lane;
    const float4* gp4 = reinterpret_cast<const float4*>(
        g2 + ((size_t)((b << 10) + jbase + j) << 4));
    float4 ga = gp4[0], gb = gp4[1], gc = gp4[2], gd = gp4[3];
    float gr[16] = {ga.x, ga.y, ga.z, ga.w, gb.x, gb.y, gb.z, gb.w,
                    gc.x, gc.y, gc.z, gc.w, gd.x, gd.y, gd.z, gd.w};
    const float* fbase = f2 + ((size_t)((b << 10) + i0) << 4);  // wave-uniform
    const int jglob = jbase + j;

#pragma unroll
    for (int q = 0; q < 2; ++q) {
      float evq[4];
#pragma unroll
      for (int u = 0; u < 4; ++u) {
        const int il = (q << 2) + u;
        const float* fr = fbase + (il << 4);
        float ps0 = 0.f, ps1 = 0.f;
        // tanh term: rcp(F*E + 1) — single trans op per term.
#define TERM(idx, dst)                                                   \
  dst = fmaf(w2s[idx],                                                   \
             __builtin_amdgcn_rcpf(fmaf(fr[idx], gr[idx], 1.0f)),        \
             dst);
        TERM(0, ps0)  TERM(1, ps0)  TERM(2, ps0)  TERM(3, ps0)
        TERM(4, ps0)  TERM(5, ps0)  TERM(6, ps0)  TERM(7, ps0)
        TERM(8, ps1)  TERM(9, ps1)  TERM(10, ps1) TERM(11, ps1)
        TERM(12, ps1) TERM(13, ps1) TERM(14, ps1) TERM(15, ps1)
#undef TERM
        const float ps = ps0 + ps1;
        evq[u] = (jglob < i0 + il) ? __builtin_amdgcn_exp2f(K - ps) : 0.f;
      }
      float4 w4;
      w4.x = evq[0]; w4.y = evq[1]; w4.z = evq[2]; w4.w = evq[3];
      esw4w[(j << 1) + q] = w4;   // es[j][q*4..q*4+3]
    }
  }

  // ---- denom: lane (part=lane>>3, ie=lane&7) sums es[part*8+jj][ie] ----
  {
    const int ie = lane & 7;
    const int part = lane >> 3;
    float dsum = 0.f;
#pragma unroll
    for (int jj = 0; jj < 8; ++jj)
      dsum += esw[(((part << 3) + jj) << 3) + ie];
    dsum += __shfl_xor(dsum, 8);
    dsum += __shfl_xor(dsum, 16);
    dsum += __shfl_xor(dsum, 32);
    if (lane < 8) pden[slot * 8 + lane] = dsum;
  }

  // ---- PV: 64 j from L2-resident x[b], es broadcast reads, packed FMA ----
  for (int blk = 0; blk < 16; ++blk) {
    const float4* xp = reinterpret_cast<const float4*>(
                           x + ((size_t)((b << 10) + jbase + (blk << 2)) << 7)) +
                       hq;
    float4 xv[4];
#pragma unroll
    for (int rr = 0; rr < 4; ++rr) xv[rr] = xp[rr << 5];  // rr*512B imm
#pragma unroll
    for (int rr = 0; rr < 4; ++rr) {
      const int jl = (blk << 2) + rr;
      union { float4 v4; f32x2 v2[2]; } ux, ue;
      ux.v4 = xv[rr];
      ue.v4 = esw4[(jl << 1) + th];  // e[il=th*4..+3][jl]
      pk_fma_bl(acc2[0], ue.v2[0], ux.v2[0]);
      pk_fma_bh(acc2[1], ue.v2[0], ux.v2[0]);
      pk_fma_bl(acc2[2], ue.v2[0], ux.v2[1]);
      pk_fma_bh(acc2[3], ue.v2[0], ux.v2[1]);
      pk_fma_bl(acc2[4], ue.v2[1], ux.v2[0]);
      pk_fma_bh(acc2[5], ue.v2[1], ux.v2[0]);
      pk_fma_bl(acc2[6], ue.v2[1], ux.v2[1]);
      pk_fma_bh(acc2[7], ue.v2[1], ux.v2[1]);
    }
  }

  // ---- write slot (8 rows x 128 cols) with non-temporal stores ----
  {
    f32x4* pacc4 = reinterpret_cast<f32x4*>(pacc);
#pragma unroll
    for (int pr = 0; pr < 2; ++pr) {
      f32x4 ve, vo;
      ve.x = acc2[pr * 4 + 0].x; ve.y = acc2[pr * 4 + 1].x;
      ve.z = acc2[pr * 4 + 2].x; ve.w = acc2[pr * 4 + 3].x;
      vo.x = acc2[pr * 4 + 0].y; vo.y = acc2[pr * 4 + 1].y;
      vo.z = acc2[pr * 4 + 2].y; vo.w = acc2[pr * 4 + 3].y;
      const int row_e = (th << 2) + (pr << 1);
      __builtin_nontemporal_store(
          ve, &pacc4[(size_t)slot * 256 + (size_t)row_e * 32 + hq]);
      __builtin_nontemporal_store(
          vo, &pacc4[(size_t)slot * 256 + (size_t)(row_e + 1) * 32 + hq]);
    }
  }
}

__global__ __launch_bounds__(256) void combine_flat9(
    const float* __restrict__ pacc, const float* __restrict__ pden,
    float* __restrict__ out) {
  const int gid = blockIdx.x * 256 + threadIdx.x;  // B*S*32
  const int row = gid >> 5;
  const int hq = gid & 31;
  const int b = row >> 10;
  const int i = row & 1023;
  const int ht = i >> 3;
  const int il = i & 7;
  const int k = ht >> 3;
  const int nseg = k + 1;
  const int pcbase = 4 * k * (k + 1) + (ht & 7) * (k + 1);
  const f32x4* pacc4 = reinterpret_cast<const f32x4*>(pacc);
  f32x4 sum = (f32x4){0.f, 0.f, 0.f, 0.f};
  float den = 0.f;
  for (int s = 0; s < nseg; ++s) {
    const int pc = pcbase + s;
    const int slot = (((pc >> 2) << 3) + b) * 4 + (pc & 3);  // bid*4+wv
    f32x4 v = __builtin_nontemporal_load(
        &pacc4[(size_t)slot * 256 + (size_t)il * 32 + hq]);
    sum += v;
    den += pden[slot * 8 + il];
  }
  const float dn = 1.0f / (den + 1e-10f);
  f32x4 o = sum * dn;
  reinterpret_cast<f32x4*>(out)[(size_t)row * 32 + hq] = o;
}

// ---------------- middle tier: segmented kernel (factorized math) ----------
__global__ __launch_bounds__(256, 5) void attn_part(
    const float* __restrict__ x, const float* __restrict__ f2,
    const float* __restrict__ g2, const float* __restrict__ w2,
    const float* __restrict__ b2, float* __restrict__ pacc,
    float* __restrict__ pden) {
  __shared__ __align__(16) float es[4][1024];
  __shared__ float denw[4][16];

  const int tid = threadIdx.x;
  const int wv = tid >> 6;
  const int lane = tid & 63;
  const int bid = blockIdx.x;
  const int b = bid & 7;
  const int sidx = 159 - (bid >> 3);
  int t, s;
  if (sidx < 16)      { t = sidx;                             s = 0; }
  else if (sidx < 48) { int u = sidx - 16; t = 16 + (u >> 1); s = u & 1; }
  else if (sidx < 96) { int u = sidx - 48; t = 32 + u / 3;    s = u - (t - 32) * 3; }
  else                { int u = sidx - 96; t = 48 + (u >> 2); s = u & 3; }
  const int i0 = t << 4;
  const int jbase0 = s << 8;
  const int nch = min(4, (i0 + 15 - jbase0 + 63) >> 6);
  const int slot = (((b << 6) + t) << 2) + s;

  const float LOG2E = 1.4426950408889634f;
  float w2s[16];
  float K;
  {
    float sw = 0.f;
#pragma unroll
    for (int a = 0; a < 16; ++a) {
      float v = w2[a];
      w2s[a] = v * (2.f * LOG2E);
      sw += v;
    }
    K = (sw + b2[0]) * LOG2E;
  }

  const int th = lane >> 5;
  const int hq = lane & 31;
  const int jbase = jbase0 + (wv << 6);
  float* esw = &es[wv][0];
  float4* esw4w = reinterpret_cast<float4*>(esw);
  const float4* esw4 = reinterpret_cast<const float4*>(esw);

  union AccU { f32x2 a2[16]; float4 a4[8]; };
  AccU acc;
#pragma unroll
  for (int p = 0; p < 8; ++p) acc.a4[p] = make_float4(0.f, 0.f, 0.f, 0.f);
  float dsum = 0.f;

  if (wv < nch) {
    const int j = lane;
    const float4* gp4 = reinterpret_cast<const float4*>(
        g2 + ((size_t)((b << 10) + jbase + j) << 4));
    float4 ga = gp4[0], gb = gp4[1], gc = gp4[2], gd = gp4[3];
    float gr[16] = {ga.x, ga.y, ga.z, ga.w, gb.x, gb.y, gb.z, gb.w,
                    gc.x, gc.y, gc.z, gc.w, gd.x, gd.y, gd.z, gd.w};
    const float* fbase = f2 + ((size_t)((b << 10) + i0) << 4);
    const int jglob = jbase + j;
    const int jswz = (j << 2);
    const int jm3 = j & 3;

#pragma unroll
    for (int q = 0; q < 4; ++q) {
      float evq[4];
#pragma unroll
      for (int u = 0; u < 4; ++u) {
        const int i = (q << 2) + u;
        const float* fr = fbase + (i << 4);
        float ps0 = 0.f, ps1 = 0.f;
#define TERM(idx, dst)                                                   \
  dst = fmaf(w2s[idx],                                                   \
             __builtin_amdgcn_rcpf(fmaf(fr[idx], gr[idx], 1.0f)),        \
             dst);
        TERM(0, ps0)  TERM(1, ps0)  TERM(2, ps0)  TERM(3, ps0)
        TERM(4, ps0)  TERM(5, ps0)  TERM(6, ps0)  TERM(7, ps0)
        TERM(8, ps1)  TERM(9, ps1)  TERM(10, ps1) TERM(11, ps1)
        TERM(12, ps1) TERM(13, ps1) TERM(14, ps1) TERM(15, ps1)
#undef TERM
        const float ps = ps0 + ps1;
        evq[u] = (jglob < i0 + i) ? __builtin_amdgcn_exp2f(K - ps) : 0.f;
      }
      float4 w4;
      w4.x = evq[0]; w4.y = evq[1]; w4.z = evq[2]; w4.w = evq[3];
      esw4w[jswz + (q ^ jm3)] = w4;
    }

    {
      const int ie = lane & 15;
      const int part = lane >> 4;
      const int iq = ie >> 2, ir = ie & 3;
#pragma unroll
      for (int jj = 0; jj < 16; ++jj) {
        const int jr = (part << 4) + jj;
        dsum += esw[(jr << 4) + ((iq ^ (jr & 3)) << 2) + ir];
      }
      dsum += __shfl_xor(dsum, 16);
      dsum += __shfl_xor(dsum, 32);
    }

    for (int blk = 0; blk < 8; ++blk) {
      const float4* xp = reinterpret_cast<const float4*>(
                             x + ((size_t)((b << 10) + jbase + (blk << 3)) << 7)) +
                         hq;
      float4 xv[8];
#pragma unroll
      for (int rr = 0; rr < 8; ++rr) xv[rr] = xp[rr << 5];
#pragma unroll
      for (int rr = 0; rr < 8; ++rr) {
        const int jl = (blk << 3) + rr;
        const int base = jl << 2;
        const int sw = jl & 3;
        union { float4 v4; f32x2 v2[2]; } ux, ua, ub;
        ux.v4 = xv[rr];
        ua.v4 = esw4[base + ((th << 1) ^ sw)];
        ub.v4 = esw4[base + (((th << 1) | 1) ^ sw)];
        pk_fma_bl(acc.a2[0], ua.v2[0], ux.v2[0]);
        pk_fma_bh(acc.a2[1], ua.v2[0], ux.v2[0]);
        pk_fma_bl(acc.a2[2], ua.v2[0], ux.v2[1]);
        pk_fma_bh(acc.a2[3], ua.v2[0], ux.v2[1]);
        pk_fma_bl(acc.a2[4], ua.v2[1], ux.v2[0]);
        pk_fma_bh(acc.a2[5], ua.v2[1], ux.v2[0]);
        pk_fma_bl(acc.a2[6], ua.v2[1], ux.v2[1]);
        pk_fma_bh(acc.a2[7], ua.v2[1], ux.v2[1]);
        pk_fma_bl(acc.a2[8], ub.v2[0], ux.v2[0]);
        pk_fma_bh(acc.a2[9], ub.v2[0], ux.v2[0]);
        pk_fma_bl(acc.a2[10], ub.v2[0], ux.v2[1]);
        pk_fma_bh(acc.a2[11], ub.v2[0], ux.v2[1]);
        pk_fma_bl(acc.a2[12], ub.v2[1], ux.v2[0]);
        pk_fma_bh(acc.a2[13], ub.v2[1], ux.v2[0]);
        pk_fma_bl(acc.a2[14], ub.v2[1], ux.v2[1]);
        pk_fma_bh(acc.a2[15], ub.v2[1], ux.v2[1]);
      }
    }
  }
  if (lane < 16) denw[wv][lane] = dsum;

  float4* esall4 = reinterpret_cast<float4*>(&es[0][0]);
  __syncthreads();
  if (wv >= 2) {
#pragma unroll
    for (int p = 0; p < 8; ++p)
      esall4[((wv - 2) << 9) + (lane << 3) + p] = acc.a4[p];
  }
  __syncthreads();
  if (wv < 2) {
#pragma unroll
    for (int p = 0; p < 8; ++p) {
      float4 v = esall4[(wv << 9) + (lane << 3) + p];
      acc.a4[p].x += v.x; acc.a4[p].y += v.y;
      acc.a4[p].z += v.z; acc.a4[p].w += v.w;
    }
  }
  __syncthreads();
  if (wv == 1) {
#pragma unroll
    for (int p = 0; p < 8; ++p) esall4[(lane << 3) + p] = acc.a4[p];
  }
  __syncthreads();
  if (wv == 0) {
#pragma unroll
    for (int p = 0; p < 8; ++p) {
      float4 v = esall4[(lane << 3) + p];
      acc.a4[p].x += v.x; acc.a4[p].y += v.y;
      acc.a4[p].z += v.z; acc.a4[p].w += v.w;
    }
    float4* pacc4 = reinterpret_cast<float4*>(pacc);
#pragma unroll
    for (int ip = 0; ip < 4; ++ip) {
      const int row_e = (th << 3) + (ip << 1);
      float4 ve, vo;
      ve.x = acc.a2[ip * 4 + 0].x; ve.y = acc.a2[ip * 4 + 1].x;
      ve.z = acc.a2[ip * 4 + 2].x; ve.w = acc.a2[ip * 4 + 3].x;
      vo.x = acc.a2[ip * 4 + 0].y; vo.y = acc.a2[ip * 4 + 1].y;
      vo.z = acc.a2[ip * 4 + 2].y; vo.w = acc.a2[ip * 4 + 3].y;
      pacc4[(size_t)slot * 512 + (size_t)row_e * 32 + hq] = ve;
      pacc4[(size_t)slot * 512 + (size_t)(row_e + 1) * 32 + hq] = vo;
    }
    if (lane < 16)
      pden[slot * 16 + lane] =
          denw[0][lane] + denw[1][lane] + denw[2][lane] + denw[3][lane];
  }
}

__global__ __launch_bounds__(256) void combine_kernel(
    const float* __restrict__ pacc, const float* __restrict__ pden,
    float* __restrict__ out) {
  const int gid = blockIdx.x * 256 + threadIdx.x;  // B*S*32
  const int row = gid >> 5;
  const int hq = gid & 31;
  const int i = row & 1023;
  const int t = i >> 4;
  const int nseg = (t >> 4) + 1;
  const int slotbase = ((row >> 10) << 8) + (t << 2);
  const float4* pacc4 = reinterpret_cast<const float4*>(pacc);
  float4 sum = make_float4(0.f, 0.f, 0.f, 0.f);
  float den = 0.f;
  for (int s = 0; s < nseg; ++s) {
    const int slot = slotbase + s;
    float4 v = pacc4[(size_t)slot * 512 + (size_t)(i & 15) * 32 + hq];
    sum.x += v.x; sum.y += v.y; sum.z += v.z; sum.w += v.w;
    den += pden[slot * 16 + (i & 15)];
  }
  const float dn = 1.0f / (den + 1e-10f);
  float4 o;
  o.x = sum.x * dn; o.y = sum.y * dn; o.z = sum.z * dn; o.w = sum.w * dn;
  reinterpret_cast<float4*>(out)[(size_t)row * 32 + hq] = o;
}

// ---------------- fallback: monolithic kernel (factorized math) ------------
__global__ __launch_bounds__(256) void attn_kernel_mono(
    const float* __restrict__ x, const float* __restrict__ f2,
    const float* __restrict__ g2, const float* __restrict__ w2,
    const float* __restrict__ b2, float* __restrict__ out) {
  __shared__ __align__(16) float xs[JC * H_];
  __shared__ __align__(16) float gsm[JC * 18];
  __shared__ __align__(16) float es2[JC * A_];
  __shared__ float dpart[4][16];
  __shared__ float denom[TI];

  const int tid = threadIdx.x;
  const int bid = blockIdx.x;
  const int tile = (S_ / TI - 1) - (bid >> 3);
  const int b = bid & 7;
  const int i0 = tile * TI;

  const float LOG2E = 1.4426950408889634f;
  float w2s[16];
  float K;
  {
    float sw = 0.f;
#pragma unroll
    for (int a = 0; a < 16; ++a) {
      float v = w2[a];
      w2s[a] = v * (2.f * LOG2E);
      sw += v;
    }
    K = (sw + b2[0]) * LOG2E;
  }

  const int ti_e = tid & 15;
  const int jq = tid >> 4;
  float f_reg[16];
  {
    const float* frow = f2 + (size_t)((b << 10) + i0 + ti_e) * A_;
#pragma unroll
    for (int a = 0; a < 16; ++a) f_reg[a] = frow[a];
  }

  const int hc = tid & 31;
  const int jg = tid >> 5;
  float4 acc[TI];
#pragma unroll
  for (int t = 0; t < TI; ++t) acc[t] = make_float4(0.f, 0.f, 0.f, 0.f);
  if (tid < TI) denom[tid] = 0.f;

  const int nch = (i0 + TI - 1 + JC - 1) / JC;
  float4* xs4 = reinterpret_cast<float4*>(xs);
  const float4* es4 = reinterpret_cast<const float4*>(es2);
  const float4* xg4 = reinterpret_cast<const float4*>(x + (size_t)(b << 10) * H_);

  for (int c = 0; c < nch; ++c) {
    const int jbase = c * JC;
    __syncthreads();
    const float4* src = xg4 + jbase * (H_ / 4);
#pragma unroll
    for (int t = 0; t < 8; ++t) xs4[tid + 256 * t] = src[tid + 256 * t];
    {
      const float4* g4p =
          reinterpret_cast<const float4*>(g2 + (size_t)((b << 10) + jbase) * A_);
      float4 g4 = g4p[tid];
      float* dst = gsm + (tid >> 2) * 18 + (tid & 3) * 4;
      dst[0] = g4.x; dst[1] = g4.y; dst[2] = g4.z; dst[3] = g4.w;
    }
    __syncthreads();

    float partial = 0.f;
#pragma unroll
    for (int k = 0; k < 4; ++k) {
      const int jl = jq * 4 + k;
      const int j = jbase + jl;
      const float* grow = gsm + jl * 18;
      float ps = 0.f;
#pragma unroll
      for (int a = 0; a < 16; ++a) {
        float r = __builtin_amdgcn_rcpf(fmaf(f_reg[a], grow[a], 1.0f));
        ps = fmaf(w2s[a], r, ps);
      }
      float ev = (j < i0 + ti_e) ? __builtin_amdgcn_exp2f(K - ps) : 0.f;
      es2[jl * A_ + ti_e] = ev;
      partial += ev;
    }
    partial += __shfl_xor(partial, 16);
    partial += __shfl_xor(partial, 32);
    if ((tid & 63) < 16) dpart[tid >> 6][ti_e] = partial;
    __syncthreads();
    if (tid < 16)
      denom[tid] += dpart[0][tid] + dpart[1][tid] + dpart[2][tid] + dpart[3][tid];

#pragma unroll 2
    for (int jj = 0; jj < 8; ++jj) {
      const int jl = jg * 8 + jj;
      float4 xv = xs4[jl * (H_ / 4) + hc];
      float4 e0 = es4[jl * 4 + 0];
      float4 e1 = es4[jl * 4 + 1];
      float4 e2v = es4[jl * 4 + 2];
      float4 e3 = es4[jl * 4 + 3];
#define FMA4_(AC, sc)                \
  AC.x = fmaf(sc, xv.x, AC.x);       \
  AC.y = fmaf(sc, xv.y, AC.y);       \
  AC.z = fmaf(sc, xv.z, AC.z);       \
  AC.w = fmaf(sc, xv.w, AC.w)
      FMA4_(acc[0], e0.x);  FMA4_(acc[1], e0.y);
      FMA4_(acc[2], e0.z);  FMA4_(acc[3], e0.w);
      FMA4_(acc[4], e1.x);  FMA4_(acc[5], e1.y);
      FMA4_(acc[6], e1.z);  FMA4_(acc[7], e1.w);
      FMA4_(acc[8], e2v.x); FMA4_(acc[9], e2v.y);
      FMA4_(acc[10], e2v.z); FMA4_(acc[11], e2v.w);
      FMA4_(acc[12], e3.x); FMA4_(acc[13], e3.y);
      FMA4_(acc[14], e3.z); FMA4_(acc[15], e3.w);
#undef FMA4_
    }
  }

  __syncthreads();
  float4* red4 = xs4;
  if (jg >= 4) {
#pragma unroll
    for (int t = 0; t < TI; ++t) red4[((jg - 4) * TI + t) * 32 + hc] = acc[t];
  }
  __syncthreads();
  if (jg < 4) {
#pragma unroll
    for (int t = 0; t < TI; ++t) {
      float4 v = red4[(jg * TI + t) * 32 + hc];
      acc[t].x += v.x; acc[t].y += v.y; acc[t].z += v.z; acc[t].w += v.w;
    }
  }
  __syncthreads();
  if (jg == 2 || jg == 3) {
#pragma unroll
    for (int t = 0; t < TI; ++t) red4[((jg - 2) * TI + t) * 32 + hc] = acc[t];
  }
  __syncthreads();
  if (jg < 2) {
#pragma unroll
    for (int t = 0; t < TI; ++t) {
      float4 v = red4[(jg * TI + t) * 32 + hc];
      acc[t].x += v.x; acc[t].y += v.y; acc[t].z += v.z; acc[t].w += v.w;
    }
  }
  __syncthreads();
  if (jg == 1) {
#pragma unroll
    for (int t = 0; t < TI; ++t) red4[t * 32 + hc] = acc[t];
  }
  __syncthreads();
  if (jg == 0) {
    float4* out4 = reinterpret_cast<float4*>(out);
#pragma unroll
    for (int t = 0; t < TI; ++t) {
      float4 v = red4[t * 32 + hc];
      float dn = 1.0f / (denom[t] + 1e-10f);
      float4 o;
      o.x = (acc[t].x + v.x) * dn;
      o.y = (acc[t].y + v.y) * dn;
      o.z = (acc[t].z + v.z) * dn;
      o.w = (acc[t].w + v.w) * dn;
      out4[(size_t)((b << 10) + i0 + t) * 32 + hc] = o;
    }
  }
}

extern "C" void kernel_launch(void* const* d_in, const int* in_sizes, int n_in,
                              void* d_out, int out_size, void* d_ws,
                              size_t ws_size, hipStream_t stream) {
  (void)in_sizes; (void)n_in; (void)out_size;
  const float* x  = (const float*)d_in[0];
  const float* W1 = (const float*)d_in[1];
  const float* b1 = (const float*)d_in[2];
  const float* w2 = (const float*)d_in[3];
  const float* b2 = (const float*)d_in[4];
  float* out = (float*)d_out;

  float* f2 = (float*)d_ws;                  // [B*S, A]  F = exp2 domain
  float* g2 = f2 + (size_t)B_ * S_ * A_;     // [B*S, A]  E = exp2 domain
  float* pacc = g2 + (size_t)B_ * S_ * A_;
  float* pden_flat = pacc + (size_t)NCH * 1024;    // NCH slots of 8x128
  float* pden_seg = pacc + (size_t)2048 * 2048;

  const size_t need_flat =
      ((size_t)B_ * S_ * A_ * 2 + (size_t)NCH * 1024 + (size_t)NCH * 8) *
      sizeof(float);
  const size_t need_seg =
      ((size_t)B_ * S_ * A_ * 2 + (size_t)2048 * 2048 + (size_t)2048 * 16) *
      sizeof(float);

  fg_kernel<<<(B_ * S_ * 32) / 256, 256, 0, stream>>>(x, W1, b1, f2, g2);
  if (ws_size >= need_flat) {
    attn_flat9<<<NCH / 4, 256, 0, stream>>>(x, f2, g2, w2, b2, pacc,
                                            pden_flat);
    combine_flat9<<<(B_ * S_ * 32) / 256, 256, 0, stream>>>(pacc, pden_flat,
                                                            out);
  } else if (ws_size >= need_seg) {
    attn_part<<<B_ * 160, 256, 0, stream>>>(x, f2, g2, w2, b2, pacc, pden_seg);
    combine_kernel<<<(B_ * S_ * 32) / 256, 256, 0, stream>>>(pacc, pden_seg,
                                                             out);
  } else {
    attn_kernel_mono<<<B_ * (S_ / TI), 256, 0, stream>>>(x, f2, g2, w2, b2, out);
  }
}

// Round 11
// 45.702 us; speedup vs baseline: 1.6543x; 1.6543x over previous
//
#include <hip/hip_runtime.h>

// ConcatenationAttention: B=8, S=1024, H=128, A=16
// out[b,i,:] = sum_{j<i} w_ij * x[b,j,:],  w = softmax over j of
//   score(i,j) = sum_a w2[a]*tanh(f[b,i,a] + g[b,j,a] + b1[a]) + b2
//
// Round 11: round-8 flat structure (best, 16i x 64j chunk-waves) with PV done
// by MFMA bf16: X pre-packed in B-fragment layout (2MB ws), e written as bf16
// to XOR-swizzled LDS in A-fragment-readable [i][j] layout, 16 MFMA per wave.
// Denom from A-fragments + 2 shuffles. Score = factorized exp2 (r8, proven).

#define B_ 8
#define S_ 1024
#define H_ 128
#define A_ 16
#define JC 64
#define CHUNKS_PER_B 544   // sum_{t<64} ceil((16t+15)/64)
#define NCHUNKS (B_ * CHUNKS_PER_B)

typedef float f32x2 __attribute__((ext_vector_type(2)));
typedef float f32x4v __attribute__((ext_vector_type(4)));
typedef short bf16x8 __attribute__((ext_vector_type(8)));

__device__ __forceinline__ unsigned short bf16_rne(float v) {
  unsigned u = __float_as_uint(v);
  u += 0x7FFFu + ((u >> 16) & 1u);
  return (unsigned short)(u >> 16);
}
__device__ __forceinline__ float bf16_tof(unsigned short h) {
  return __uint_as_float(((unsigned)h) << 16);
}

// acc += e2 * broadcast(x2.lo)   (fallback tiers)
__device__ __forceinline__ void pk_fma_bl(f32x2& acc, f32x2 e2, f32x2 x2) {
  asm volatile("v_pk_fma_f32 %0, %1, %2, %0 op_sel:[0,0,0] op_sel_hi:[1,0,1]"
               : "+v"(acc) : "v"(e2), "v"(x2));
}
__device__ __forceinline__ void pk_fma_bh(f32x2& acc, f32x2 e2, f32x2 x2) {
  asm volatile("v_pk_fma_f32 %0, %1, %2, %0 op_sel:[0,1,0] op_sel_hi:[1,1,1]"
               : "+v"(acc) : "v"(e2), "v"(x2));
}

__global__ __launch_bounds__(256) void fg_kernel(
    const float* __restrict__ x, const float* __restrict__ W1,
    const float* __restrict__ b1, float* __restrict__ f2,
    float* __restrict__ g2) {
  int gid = blockIdx.x * 256 + threadIdx.x;   // B*S*32 threads
  int row = gid >> 5;                         // b*S + s
  int q = gid & 31;
  int a = q & 15;
  int half = q >> 4;
  const float4* x4 = reinterpret_cast<const float4*>(x + (size_t)row * H_);
  const float* w = W1 + half * H_ * A_ + a;   // column a, stride A_
  float s = 0.f;
#pragma unroll 4
  for (int hi = 0; hi < H_ / 4; ++hi) {
    float4 xv = x4[hi];
    s = fmaf(xv.x, w[(hi * 4 + 0) * A_], s);
    s = fmaf(xv.y, w[(hi * 4 + 1) * A_], s);
    s = fmaf(xv.z, w[(hi * 4 + 2) * A_], s);
    s = fmaf(xv.w, w[(hi * 4 + 3) * A_], s);
  }
  const float TANH_C = 2.8853900817779268f;   // 2*log2(e)
  // exp2-domain: F = exp2((f+b1)*C), E = exp2(g*C)
  if (half == 0)
    f2[row * A_ + a] = __builtin_amdgcn_exp2f((s + b1[a]) * TANH_C);
  else
    g2[row * A_ + a] = __builtin_amdgcn_exp2f(s * TANH_C);
}

// X -> bf16 B-fragment layout: xfrag[((b*32+jt)*8+nt)*64+lane][e] =
//   bf16(x[b][jt*32 + (lane>>4)*8 + e][nt*16 + (lane&15)])
__global__ __launch_bounds__(256) void xfrag_kernel(
    const float* __restrict__ x, unsigned short* __restrict__ xfrag) {
  const int gid = blockIdx.x * 256 + threadIdx.x;  // 131072 threads
  const int lane = gid & 63;
  const int nt = (gid >> 6) & 7;
  const int jt = (gid >> 9) & 31;
  const int b = gid >> 14;
  const int col = (nt << 4) + (lane & 15);
  const int j0 = (jt << 5) + ((lane >> 4) << 3);
  const float* xp = x + ((size_t)((b << 10) + j0) << 7) + col;
  union { unsigned short u[8]; uint4 v; } r;
#pragma unroll
  for (int e = 0; e < 8; ++e) r.u[e] = bf16_rne(xp[(size_t)e << 7]);
  reinterpret_cast<uint4*>(xfrag)[gid] = r.v;
}

// -------- round 11: flat chunk kernel, MFMA PV ------------------------------
__global__ __launch_bounds__(256, 5) void attn_mfma(
    const float* __restrict__ f2, const float* __restrict__ g2,
    const unsigned short* __restrict__ xfrag, const float* __restrict__ w2,
    const float* __restrict__ b2, float* __restrict__ pacc,
    float* __restrict__ pden) {
  // per-wave 2KB: e as bf16, [i][j] with byte ^= (i&7)<<4 swizzle
  __shared__ __align__(16) unsigned short esb[4][1024];

  const int tid = threadIdx.x;
  const int wv = tid >> 6;
  const int lane = tid & 63;
  const int w = (NCHUNKS - 1) - (blockIdx.x * 4 + wv);
  const int b = w / CHUNKS_PER_B;
  const int cid = w - b * CHUNKS_PER_B;
  int k = (int)((__builtin_sqrtf(2.f * (float)cid + 1.f) - 1.f) * 0.5f);
  while (2 * (k + 1) * (k + 2) <= cid) ++k;
  while (2 * k * (k + 1) > cid) --k;
  const int rem = cid - 2 * k * (k + 1);
  const int r = rem / (k + 1);
  const int c = rem - r * (k + 1);
  const int t = (k << 2) + r;
  const int i0 = t << 4;
  const int jbase = c << 6;
  const int slot = w;

  const float LOG2E = 1.4426950408889634f;
  float w2s[16];
  float K;
  {
    float sw = 0.f;
#pragma unroll
    for (int a = 0; a < 16; ++a) {
      float v = w2[a];
      w2s[a] = v * (2.f * LOG2E);
      sw += v;
    }
    K = (sw + b2[0]) * LOG2E;
  }

  char* esbase = reinterpret_cast<char*>(&esb[wv][0]);

  // ---- score: lane owns column j; 1 trans/term; bf16 -> swizzled LDS ----
  {
    const int j = lane;
    const float4* gp4 = reinterpret_cast<const float4*>(
        g2 + ((size_t)((b << 10) + jbase + j) << 4));
    float4 ga = gp4[0], gb = gp4[1], gc = gp4[2], gd = gp4[3];
    float gr[16] = {ga.x, ga.y, ga.z, ga.w, gb.x, gb.y, gb.z, gb.w,
                    gc.x, gc.y, gc.z, gc.w, gd.x, gd.y, gd.z, gd.w};
    const float* fbase = f2 + ((size_t)((b << 10) + i0) << 4);  // wave-uniform
    const int jglob = jbase + j;
    const int jx2 = j << 1;
#pragma unroll
    for (int i = 0; i < 16; ++i) {
      const float* fr = fbase + (i << 4);
      float ps0 = 0.f, ps1 = 0.f;
#define TERM(idx, dst)                                                   \
  dst = fmaf(w2s[idx],                                                   \
             __builtin_amdgcn_rcpf(fmaf(fr[idx], gr[idx], 1.0f)),        \
             dst);
      TERM(0, ps0)  TERM(1, ps0)  TERM(2, ps0)  TERM(3, ps0)
      TERM(4, ps0)  TERM(5, ps0)  TERM(6, ps0)  TERM(7, ps0)
      TERM(8, ps1)  TERM(9, ps1)  TERM(10, ps1) TERM(11, ps1)
      TERM(12, ps1) TERM(13, ps1) TERM(14, ps1) TERM(15, ps1)
#undef TERM
      float ev =
          (jglob < i0 + i) ? __builtin_amdgcn_exp2f(K - (ps0 + ps1)) : 0.f;
      *reinterpret_cast<unsigned short*>(
          esbase + (((i << 7) + jx2) ^ ((i & 7) << 4))) = bf16_rne(ev);
    }
  }

  // ---- A-fragments: lane li=i row, g=k-group; ds_read_b128 per k-tile ----
  const int li = lane & 15;
  const int g = lane >> 4;
  const int cxor = (li & 7) << 4;
  const int off0 = ((li << 7) + (g << 4)) ^ cxor;         // k-tile 0 (j 0..31)
  const int off1 = ((li << 7) + 64 + (g << 4)) ^ cxor;    // k-tile 1 (j 32..63)
  bf16x8 a0 = *reinterpret_cast<const bf16x8*>(esbase + off0);
  bf16x8 a1 = *reinterpret_cast<const bf16x8*>(esbase + off1);

  // ---- denom from fragments (consistent bf16 rounding with numerator) ----
  {
    float dsum = 0.f;
#pragma unroll
    for (int e = 0; e < 8; ++e)
      dsum += bf16_tof((unsigned short)a0[e]) + bf16_tof((unsigned short)a1[e]);
    dsum += __shfl_xor(dsum, 16);
    dsum += __shfl_xor(dsum, 32);
    if (lane < 16) pden[slot * 16 + lane] = dsum;
  }

  // ---- PV: 16 MFMA (8 n-tiles x 2 k-tiles), B from pre-packed xfrag ----
  f32x4v acc[8];
#pragma unroll
  for (int nt = 0; nt < 8; ++nt) acc[nt] = (f32x4v){0.f, 0.f, 0.f, 0.f};
  const bf16x8* xf = reinterpret_cast<const bf16x8*>(xfrag) +
                     (((size_t)(b << 5) + (size_t)(jbase >> 5)) << 9) + lane;
#pragma unroll
  for (int nt = 0; nt < 8; ++nt) {
    bf16x8 bf0 = xf[(size_t)(nt << 6)];
    bf16x8 bf1 = xf[(size_t)(nt << 6) + 512];
    acc[nt] = __builtin_amdgcn_mfma_f32_16x16x32_bf16(a0, bf0, acc[nt], 0, 0, 0);
    acc[nt] = __builtin_amdgcn_mfma_f32_16x16x32_bf16(a1, bf1, acc[nt], 0, 0, 0);
  }

  // ---- store: C row = g*4+rr (i), col = nt*16+li (h) ----
  {
    float* pb = pacc + (size_t)slot * 2048 + (size_t)(g << 2) * 128 + li;
#pragma unroll
    for (int nt = 0; nt < 8; ++nt) {
#pragma unroll
      for (int rr = 0; rr < 4; ++rr)
        pb[rr * 128 + (nt << 4)] = acc[nt][rr];
    }
  }
}

__global__ __launch_bounds__(256) void combine_flat(
    const float* __restrict__ pacc, const float* __restrict__ pden,
    float* __restrict__ out) {
  const int gid = blockIdx.x * 256 + threadIdx.x;  // B*S*32
  const int row = gid >> 5;
  const int hq = gid & 31;
  const int b = row >> 10;
  const int i = row & 1023;
  const int t = i >> 4;
  const int k = t >> 2;
  const int nseg = k + 1;
  const int slotbase = b * CHUNKS_PER_B + 2 * k * (k + 1) + (t & 3) * (k + 1);
  const float4* pacc4 = reinterpret_cast<const float4*>(pacc);
  float4 sum = make_float4(0.f, 0.f, 0.f, 0.f);
  float den = 0.f;
  for (int s = 0; s < nseg; ++s) {
    const int slot = slotbase + s;
    float4 v = pacc4[(size_t)slot * 512 + (size_t)(i & 15) * 32 + hq];
    sum.x += v.x; sum.y += v.y; sum.z += v.z; sum.w += v.w;
    den += pden[slot * 16 + (i & 15)];
  }
  const float dn = 1.0f / (den + 1e-10f);
  float4 o;
  o.x = sum.x * dn; o.y = sum.y * dn; o.z = sum.z * dn; o.w = sum.w * dn;
  reinterpret_cast<float4*>(out)[(size_t)row * 32 + hq] = o;
}

// ---------------- fallback tier: round-8 flat scalar kernel ----------------
__global__ __launch_bounds__(256, 5) void attn_flat(
    const float* __restrict__ x, const float* __restrict__ f2,
    const float* __restrict__ g2, const float* __restrict__ w2,
    const float* __restrict__ b2, float* __restrict__ pacc,
    float* __restrict__ pden) {
  __shared__ __align__(16) float es[4][1024];

  const int tid = threadIdx.x;
  const int wv = tid >> 6;
  const int lane = tid & 63;
  const int w = (NCHUNKS - 1) - (blockIdx.x * 4 + wv);
  const int b = w / CHUNKS_PER_B;
  const int cid = w - b * CHUNKS_PER_B;
  int k = (int)((__builtin_sqrtf(2.f * (float)cid + 1.f) - 1.f) * 0.5f);
  while (2 * (k + 1) * (k + 2) <= cid) ++k;
  while (2 * k * (k + 1) > cid) --k;
  const int rem = cid - 2 * k * (k + 1);
  const int r = rem / (k + 1);
  const int c = rem - r * (k + 1);
  const int t = (k << 2) + r;
  const int i0 = t << 4;
  const int jbase = c << 6;
  const int slot = w;

  const float LOG2E = 1.4426950408889634f;
  float w2s[16];
  float K;
  {
    float sw = 0.f;
#pragma unroll
    for (int a = 0; a < 16; ++a) {
      float v = w2[a];
      w2s[a] = v * (2.f * LOG2E);
      sw += v;
    }
    K = (sw + b2[0]) * LOG2E;
  }

  const int th = lane >> 5;
  const int hq = lane & 31;
  float* esw = &es[wv][0];
  float4* esw4w = reinterpret_cast<float4*>(esw);
  const float4* esw4 = reinterpret_cast<const float4*>(esw);

  union AccU { f32x2 a2[16]; float4 a4[8]; };
  AccU acc;
#pragma unroll
  for (int p = 0; p < 8; ++p) acc.a4[p] = make_float4(0.f, 0.f, 0.f, 0.f);
  float dsum = 0.f;

  {
    const int j = lane;
    const float4* gp4 = reinterpret_cast<const float4*>(
        g2 + ((size_t)((b << 10) + jbase + j) << 4));
    float4 ga = gp4[0], gb = gp4[1], gc = gp4[2], gd = gp4[3];
    float gr[16] = {ga.x, ga.y, ga.z, ga.w, gb.x, gb.y, gb.z, gb.w,
                    gc.x, gc.y, gc.z, gc.w, gd.x, gd.y, gd.z, gd.w};
    const float* fbase = f2 + ((size_t)((b << 10) + i0) << 4);
    const int jglob = jbase + j;
    const int jswz = (j << 2);
    const int jm3 = j & 3;

#pragma unroll
    for (int q = 0; q < 4; ++q) {
      float evq[4];
#pragma unroll
      for (int u = 0; u < 4; ++u) {
        const int i = (q << 2) + u;
        const float* fr = fbase + (i << 4);
        float ps0 = 0.f, ps1 = 0.f;
#define TERM(idx, dst)                                                   \
  dst = fmaf(w2s[idx],                                                   \
             __builtin_amdgcn_rcpf(fmaf(fr[idx], gr[idx], 1.0f)),        \
             dst);
        TERM(0, ps0)  TERM(1, ps0)  TERM(2, ps0)  TERM(3, ps0)
        TERM(4, ps0)  TERM(5, ps0)  TERM(6, ps0)  TERM(7, ps0)
        TERM(8, ps1)  TERM(9, ps1)  TERM(10, ps1) TERM(11, ps1)
        TERM(12, ps1) TERM(13, ps1) TERM(14, ps1) TERM(15, ps1)
#undef TERM
        const float ps = ps0 + ps1;
        evq[u] = (jglob < i0 + i) ? __builtin_amdgcn_exp2f(K - ps) : 0.f;
      }
      float4 w4;
      w4.x = evq[0]; w4.y = evq[1]; w4.z = evq[2]; w4.w = evq[3];
      esw4w[jswz + (q ^ jm3)] = w4;
    }
  }

  {
    const int ie = lane & 15;
    const int part = lane >> 4;
    const int iq = ie >> 2, ir = ie & 3;
#pragma unroll
    for (int jj = 0; jj < 16; ++jj) {
      const int jr = (part << 4) + jj;
      dsum += esw[(jr << 4) + ((iq ^ (jr & 3)) << 2) + ir];
    }
    dsum += __shfl_xor(dsum, 16);
    dsum += __shfl_xor(dsum, 32);
  }
  if (lane < 16) pden[slot * 16 + lane] = dsum;

  for (int blk = 0; blk < 8; ++blk) {
    const float4* xp = reinterpret_cast<const float4*>(
                           x + ((size_t)((b << 10) + jbase + (blk << 3)) << 7)) +
                       hq;
    float4 xv[8];
#pragma unroll
    for (int rr = 0; rr < 8; ++rr) xv[rr] = xp[rr << 5];
#pragma unroll
    for (int rr = 0; rr < 8; ++rr) {
      const int jl = (blk << 3) + rr;
      const int base = jl << 2;
      const int sw = jl & 3;
      union { float4 v4; f32x2 v2[2]; } ux, ua, ub;
      ux.v4 = xv[rr];
      ua.v4 = esw4[base + ((th << 1) ^ sw)];
      ub.v4 = esw4[base + (((th << 1) | 1) ^ sw)];
      pk_fma_bl(acc.a2[0], ua.v2[0], ux.v2[0]);
      pk_fma_bh(acc.a2[1], ua.v2[0], ux.v2[0]);
      pk_fma_bl(acc.a2[2], ua.v2[0], ux.v2[1]);
      pk_fma_bh(acc.a2[3], ua.v2[0], ux.v2[1]);
      pk_fma_bl(acc.a2[4], ua.v2[1], ux.v2[0]);
      pk_fma_bh(acc.a2[5], ua.v2[1], ux.v2[0]);
      pk_fma_bl(acc.a2[6], ua.v2[1], ux.v2[1]);
      pk_fma_bh(acc.a2[7], ua.v2[1], ux.v2[1]);
      pk_fma_bl(acc.a2[8], ub.v2[0], ux.v2[0]);
      pk_fma_bh(acc.a2[9], ub.v2[0], ux.v2[0]);
      pk_fma_bl(acc.a2[10], ub.v2[0], ux.v2[1]);
      pk_fma_bh(acc.a2[11], ub.v2[0], ux.v2[1]);
      pk_fma_bl(acc.a2[12], ub.v2[1], ux.v2[0]);
      pk_fma_bh(acc.a2[13], ub.v2[1], ux.v2[0]);
      pk_fma_bl(acc.a2[14], ub.v2[1], ux.v2[1]);
      pk_fma_bh(acc.a2[15], ub.v2[1], ux.v2[1]);
    }
  }

  {
    float4* pacc4 = reinterpret_cast<float4*>(pacc);
#pragma unroll
    for (int ip = 0; ip < 4; ++ip) {
      const int row_e = (th << 3) + (ip << 1);
      float4 ve, vo;
      ve.x = acc.a2[ip * 4 + 0].x; ve.y = acc.a2[ip * 4 + 1].x;
      ve.z = acc.a2[ip * 4 + 2].x; ve.w = acc.a2[ip * 4 + 3].x;
      vo.x = acc.a2[ip * 4 + 0].y; vo.y = acc.a2[ip * 4 + 1].y;
      vo.z = acc.a2[ip * 4 + 2].y; vo.w = acc.a2[ip * 4 + 3].y;
      pacc4[(size_t)slot * 512 + (size_t)row_e * 32 + hq] = ve;
      pacc4[(size_t)slot * 512 + (size_t)(row_e + 1) * 32 + hq] = vo;
    }
  }
}

// ---------------- fallback: monolithic kernel (factorized math) ------------
__global__ __launch_bounds__(256) void attn_kernel_mono(
    const float* __restrict__ x, const float* __restrict__ f2,
    const float* __restrict__ g2, const float* __restrict__ w2,
    const float* __restrict__ b2, float* __restrict__ out) {
  __shared__ __align__(16) float xs[JC * H_];
  __shared__ __align__(16) float gsm[JC * 18];
  __shared__ __align__(16) float es2[JC * A_];
  __shared__ float dpart[4][16];
  __shared__ float denom[16];

  const int tid = threadIdx.x;
  const int bid = blockIdx.x;
  const int tile = 63 - (bid >> 3);
  const int b = bid & 7;
  const int i0 = tile * 16;

  const float LOG2E = 1.4426950408889634f;
  float w2s[16];
  float K;
  {
    float sw = 0.f;
#pragma unroll
    for (int a = 0; a < 16; ++a) {
      float v = w2[a];
      w2s[a] = v * (2.f * LOG2E);
      sw += v;
    }
    K = (sw + b2[0]) * LOG2E;
  }

  const int ti_e = tid & 15;
  const int jq = tid >> 4;
  float f_reg[16];
  {
    const float* frow = f2 + (size_t)((b << 10) + i0 + ti_e) * A_;
#pragma unroll
    for (int a = 0; a < 16; ++a) f_reg[a] = frow[a];
  }

  const int hc = tid & 31;
  const int jg = tid >> 5;
  float4 acc[16];
#pragma unroll
  for (int t = 0; t < 16; ++t) acc[t] = make_float4(0.f, 0.f, 0.f, 0.f);
  if (tid < 16) denom[tid] = 0.f;

  const int nch = (i0 + 15 + JC - 1) / JC;
  float4* xs4 = reinterpret_cast<float4*>(xs);
  const float4* es4 = reinterpret_cast<const float4*>(es2);
  const float4* xg4 = reinterpret_cast<const float4*>(x + (size_t)(b << 10) * H_);

  for (int c = 0; c < nch; ++c) {
    const int jbase = c * JC;
    __syncthreads();
    const float4* src = xg4 + jbase * (H_ / 4);
#pragma unroll
    for (int t = 0; t < 8; ++t) xs4[tid + 256 * t] = src[tid + 256 * t];
    {
      const float4* g4p =
          reinterpret_cast<const float4*>(g2 + (size_t)((b << 10) + jbase) * A_);
      float4 g4 = g4p[tid];
      float* dst = gsm + (tid >> 2) * 18 + (tid & 3) * 4;
      dst[0] = g4.x; dst[1] = g4.y; dst[2] = g4.z; dst[3] = g4.w;
    }
    __syncthreads();

    float partial = 0.f;
#pragma unroll
    for (int k = 0; k < 4; ++k) {
      const int jl = jq * 4 + k;
      const int j = jbase + jl;
      const float* grow = gsm + jl * 18;
      float ps = 0.f;
#pragma unroll
      for (int a = 0; a < 16; ++a) {
        float rr = __builtin_amdgcn_rcpf(fmaf(f_reg[a], grow[a], 1.0f));
        ps = fmaf(w2s[a], rr, ps);
      }
      float ev = (j < i0 + ti_e) ? __builtin_amdgcn_exp2f(K - ps) : 0.f;
      es2[jl * A_ + ti_e] = ev;
      partial += ev;
    }
    partial += __shfl_xor(partial, 16);
    partial += __shfl_xor(partial, 32);
    if ((tid & 63) < 16) dpart[tid >> 6][ti_e] = partial;
    __syncthreads();
    if (tid < 16)
      denom[tid] += dpart[0][tid] + dpart[1][tid] + dpart[2][tid] + dpart[3][tid];

#pragma unroll 2
    for (int jj = 0; jj < 8; ++jj) {
      const int jl = jg * 8 + jj;
      float4 xv = xs4[jl * (H_ / 4) + hc];
      float4 e0 = es4[jl * 4 + 0];
      float4 e1 = es4[jl * 4 + 1];
      float4 e2v = es4[jl * 4 + 2];
      float4 e3 = es4[jl * 4 + 3];
#define FMA4_(AC, sc)                \
  AC.x = fmaf(sc, xv.x, AC.x);       \
  AC.y = fmaf(sc, xv.y, AC.y);       \
  AC.z = fmaf(sc, xv.z, AC.z);       \
  AC.w = fmaf(sc, xv.w, AC.w)
      FMA4_(acc[0], e0.x);  FMA4_(acc[1], e0.y);
      FMA4_(acc[2], e0.z);  FMA4_(acc[3], e0.w);
      FMA4_(acc[4], e1.x);  FMA4_(acc[5], e1.y);
      FMA4_(acc[6], e1.z);  FMA4_(acc[7], e1.w);
      FMA4_(acc[8], e2v.x); FMA4_(acc[9], e2v.y);
      FMA4_(acc[10], e2v.z); FMA4_(acc[11], e2v.w);
      FMA4_(acc[12], e3.x); FMA4_(acc[13], e3.y);
      FMA4_(acc[14], e3.z); FMA4_(acc[15], e3.w);
#undef FMA4_
    }
  }

  __syncthreads();
  float4* red4 = xs4;
  if (jg >= 4) {
#pragma unroll
    for (int t = 0; t < 16; ++t) red4[((jg - 4) * 16 + t) * 32 + hc] = acc[t];
  }
  __syncthreads();
  if (jg < 4) {
#pragma unroll
    for (int t = 0; t < 16; ++t) {
      float4 v = red4[(jg * 16 + t) * 32 + hc];
      acc[t].x += v.x; acc[t].y += v.y; acc[t].z += v.z; acc[t].w += v.w;
    }
  }
  __syncthreads();
  if (jg == 2 || jg == 3) {
#pragma unroll
    for (int t = 0; t < 16; ++t) red4[((jg - 2) * 16 + t) * 32 + hc] = acc[t];
  }
  __syncthreads();
  if (jg < 2) {
#pragma unroll
    for (int t = 0; t < 16; ++t) {
      float4 v = red4[(jg * 16 + t) * 32 + hc];
      acc[t].x += v.x; acc[t].y += v.y; acc[t].z += v.z; acc[t].w += v.w;
    }
  }
  __syncthreads();
  if (jg == 1) {
#pragma unroll
    for (int t = 0; t < 16; ++t) red4[t * 32 + hc] = acc[t];
  }
  __syncthreads();
  if (jg == 0) {
    float4* out4 = reinterpret_cast<float4*>(out);
#pragma unroll
    for (int t = 0; t < 16; ++t) {
      float4 v = red4[t * 32 + hc];
      float dn = 1.0f / (denom[t] + 1e-10f);
      float4 o;
      o.x = (acc[t].x + v.x) * dn;
      o.y = (acc[t].y + v.y) * dn;
      o.z = (acc[t].z + v.z) * dn;
      o.w = (acc[t].w + v.w) * dn;
      out4[(size_t)((b << 10) + i0 + t) * 32 + hc] = o;
    }
  }
}

extern "C" void kernel_launch(void* const* d_in, const int* in_sizes, int n_in,
                              void* d_out, int out_size, void* d_ws,
                              size_t ws_size, hipStream_t stream) {
  (void)in_sizes; (void)n_in; (void)out_size;
  const float* x  = (const float*)d_in[0];
  const float* W1 = (const float*)d_in[1];
  const float* b1 = (const float*)d_in[2];
  const float* w2 = (const float*)d_in[3];
  const float* b2 = (const float*)d_in[4];
  float* out = (float*)d_out;

  float* f2 = (float*)d_ws;                  // [B*S, A]  F = exp2 domain
  float* g2 = f2 + (size_t)B_ * S_ * A_;     // [B*S, A]  E = exp2 domain
  // mfma layout: xfrag (2MB) then pacc/pden
  unsigned short* xfrag = (unsigned short*)(g2 + (size_t)B_ * S_ * A_);
  float* pacc_m = (float*)(xfrag + (size_t)1048576);  // 8*32*8*64*8 ushorts
  float* pden_m = pacc_m + (size_t)NCHUNKS * 2048;
  // flat8 layout: pacc right after g2
  float* pacc_f = g2 + (size_t)B_ * S_ * A_;
  float* pden_f = pacc_f + (size_t)NCHUNKS * 2048;

  const size_t need_mfma =
      ((size_t)B_ * S_ * A_ * 2 + 524288 /*xfrag as floats*/ +
       (size_t)NCHUNKS * 2048 + (size_t)NCHUNKS * 16) * sizeof(float);
  const size_t need_flat =
      ((size_t)B_ * S_ * A_ * 2 + (size_t)NCHUNKS * 2048 +
       (size_t)NCHUNKS * 16) * sizeof(float);

  fg_kernel<<<(B_ * S_ * 32) / 256, 256, 0, stream>>>(x, W1, b1, f2, g2);
  if (ws_size >= need_mfma) {
    xfrag_kernel<<<512, 256, 0, stream>>>(x, xfrag);
    attn_mfma<<<NCHUNKS / 4, 256, 0, stream>>>(f2, g2, xfrag, w2, b2, pacc_m,
                                               pden_m);
    combine_flat<<<(B_ * S_ * 32) / 256, 256, 0, stream>>>(pacc_m, pden_m, out);
  } else if (ws_size >= need_flat) {
    attn_flat<<<NCHUNKS / 4, 256, 0, stream>>>(x, f2, g2, w2, b2, pacc_f,
                                               pden_f);
    combine_flat<<<(B_ * S_ * 32) / 256, 256, 0, stream>>>(pacc_f, pden_f, out);
  } else {
    attn_kernel_mono<<<B_ * 64, 256, 0, stream>>>(x, f2, g2, w2, b2, out);
  }
}